// Round 6
// baseline (1293.918 us; speedup 1.0000x reference)
//
#include <hip/hip_runtime.h>
#include <hip/hip_bf16.h>
#include <float.h>
#include <limits.h>

// ---- problem constants ----
#define NROWS 3136        // 64 items * 49 positions
#define NROWS_PAD 3200    // padded to 25 * 128 for GEMM tiles
#define NKEYS 65536
#define KDIM 512
#define NITEMS 64
#define HW 49
#define TOPK 16
#define CAND 32           // candidates kept per row (margin for exact rescore)
#define TCAP 1024         // LDS collection buffer capacity per row
#define CHUNK_MAX 16384   // keys per chunk: 3200*16384*2 = 100 MB sims slab, L3-resident
#define ALPHA_C 0.1f

typedef unsigned short u16;
typedef unsigned int u32;
typedef __attribute__((ext_vector_type(8))) short bfrag;   // 8 bf16 = 4 VGPR (MFMA A/B frag)
typedef __attribute__((ext_vector_type(4))) float f32x4;   // MFMA C/D frag

// round-to-nearest-even f32 -> bf16 bits (inputs finite)
__device__ inline u16 f2bf(float x) {
  u32 u = __float_as_uint(x);
  u32 r = u + 0x7fffu + ((u >> 16) & 1u);
  return (u16)(r >> 16);
}

// ---------------- prep: normalize queries ----------------
// queries layout (64, 512, 7, 7): q[b,p,c] = queries[b*512*49 + c*49 + p]
__global__ __launch_bounds__(256) void prep_qnorm(const float* __restrict__ q,
        float* __restrict__ q_norm, u16* __restrict__ qbf) {
  int row = blockIdx.x;
  int t = threadIdx.x;
  if (row >= NROWS) {            // pad rows: zero bf16 so GEMM is defined
    qbf[(size_t)row * KDIM + t] = 0;
    qbf[(size_t)row * KDIM + t + 256] = 0;
    return;
  }
  int b = row / HW, p = row % HW;
  const float* base = q + (size_t)b * KDIM * HW + p;
  float v0 = base[(size_t)t * HW];
  float v1 = base[(size_t)(t + 256) * HW];
  __shared__ float red[256];
  red[t] = v0 * v0 + v1 * v1;
  __syncthreads();
  for (int st = 128; st > 0; st >>= 1) {
    if (t < st) red[t] += red[t + st];
    __syncthreads();
  }
  float nrm = fmaxf(sqrtf(red[0]), 1e-12f);   // clip(norm, 1e-12)
  float w0 = v0 / nrm, w1 = v1 / nrm;
  q_norm[(size_t)row * KDIM + t] = w0;
  q_norm[(size_t)row * KDIM + t + 256] = w1;
  qbf[(size_t)row * KDIM + t] = f2bf(w0);
  qbf[(size_t)row * KDIM + t + 256] = f2bf(w1);
}

// ---------------- prep: keys -> bf16 ----------------
__global__ __launch_bounds__(256) void prep_keys(const float* __restrict__ mk, u16* __restrict__ kbf) {
  size_t i = ((size_t)blockIdx.x * 256 + threadIdx.x) * 8;
  float4 a = *(const float4*)(mk + i);
  float4 b = *(const float4*)(mk + i + 4);
  bfrag v;
  v[0] = (short)f2bf(a.x); v[1] = (short)f2bf(a.y);
  v[2] = (short)f2bf(a.z); v[3] = (short)f2bf(a.w);
  v[4] = (short)f2bf(b.x); v[5] = (short)f2bf(b.y);
  v[6] = (short)f2bf(b.z); v[7] = (short)f2bf(b.w);
  *(bfrag*)(kbf + i) = v;
}

// ---------------- misc init / class scan ----------------
__global__ void init_first(int* first_idx) {
  int t = threadIdx.x;
  if (t < 100) first_idx[t] = INT_MAX;
}
__global__ __launch_bounds__(256) void init_run(float* run_sim, int* run_idx) {
  int i = blockIdx.x * 256 + threadIdx.x;   // NROWS*CAND entries exactly
  run_sim[i] = -FLT_MAX;
  run_idx[i] = INT_MAX;
}
__global__ __launch_bounds__(256) void scan_vals(const int* __restrict__ mvals, int* first_idx) {
  int i = blockIdx.x * 256 + threadIdx.x;
  atomicMin(&first_idx[mvals[i]], i);       // first occurrence == argmax(hit)
}
__global__ void item_info(const int* __restrict__ targets, const int* __restrict__ first_idx,
                          int* item_saf, int* item_ex) {
  int b = threadIdx.x;   // 64
  int fi = first_idx[targets[b]];
  int ex = (fi != INT_MAX);
  item_ex[b] = ex;
  item_saf[b] = ex ? fi : 0;   // argmax(all-False) == 0 in reference
}

// ---------------- bf16 MFMA GEMM: sims chunk = qbf @ kbf^T (bf16 out) ----------------
// m97-style 128x128 tile, BK=32, 4 waves (each 64x64 via 4x4 16x16x32 frags),
// global_load_lds width 16, linear LDS. Grid: x = row-panel (25, fastest) so
// consecutive blocks reuse one B-tile from L2; y = key-tile.
__device__ inline void gload16(const void* g, void* l) {
  __builtin_amdgcn_global_load_lds((const __attribute__((address_space(1))) unsigned int*)g,
                                   (__attribute__((address_space(3))) unsigned int*)l, 16, 0, 0);
}

#define CT_LD 144   // u16 elements per Ct row (288B; keeps 16B alignment per row)

__global__ __launch_bounds__(256) void gemm_chunk(const u16* __restrict__ A, const u16* __restrict__ B,
        u16* __restrict__ C, int ldc) {
  __shared__ __align__(16) char lds[128 * CT_LD * 2];   // 36864 B; aliases As/Bs then Ct
  u16* As = (u16*)lds;                                  // [128][32]
  u16* Bs = (u16*)(lds + 8192);                         // [128][32]
  u16* Ct = (u16*)lds;                                  // [128][CT_LD]
  int tid = threadIdx.x;
  int lane = tid & 63, wv = tid >> 6;
  int wr = wv >> 1, wc = wv & 1;
  int mbase = blockIdx.x * 128;   // row panel (fastest-varying)
  int nbase = blockIdx.y * 128;   // key tile
  const u16* Ag = A + (size_t)mbase * KDIM;
  const u16* Bg = B + (size_t)nbase * KDIM;

  f32x4 acc[4][4];
  #pragma unroll
  for (int i = 0; i < 4; ++i)
    #pragma unroll
    for (int j = 0; j < 4; ++j)
      acc[i][j] = (f32x4){0.f, 0.f, 0.f, 0.f};

  int lrow = lane & 15;
  int k8 = (lane >> 4) * 8;     // contiguous 8-bf16 K-slice per lane

  for (int kk = 0; kk < KDIM; kk += 32) {
    #pragma unroll
    for (int s = 0; s < 2; ++s) {
      int ch = s * 256 + wv * 64 + lane;      // 512 x 16B chunks per 8KB tile
      int r = ch >> 2, c = (ch & 3) * 8;
      gload16(Ag + (size_t)r * KDIM + kk + c, lds + (size_t)(s * 256 + wv * 64) * 16);
      gload16(Bg + (size_t)r * KDIM + kk + c, lds + 8192 + (size_t)(s * 256 + wv * 64) * 16);
    }
    __syncthreads();
    bfrag a[4], b[4];
    #pragma unroll
    for (int i = 0; i < 4; ++i) {
      a[i] = *(const bfrag*)&As[(wr * 64 + i * 16 + lrow) * 32 + k8];
      b[i] = *(const bfrag*)&Bs[(wc * 64 + i * 16 + lrow) * 32 + k8];
    }
    #pragma unroll
    for (int i = 0; i < 4; ++i)
      #pragma unroll
      for (int j = 0; j < 4; ++j)
        acc[i][j] = __builtin_amdgcn_mfma_f32_16x16x32_bf16(a[i], b[j], acc[i][j], 0, 0, 0);
    __syncthreads();   // also protects the Ct alias below on the last iteration
  }
  // C/D layout: col = lane&15, row = (lane>>4)*4 + reg  [m89-verified]
  int r0l = wr * 64 + (lane >> 4) * 4;
  int c0l = wc * 64 + lrow;
  #pragma unroll
  for (int i = 0; i < 4; ++i)
    #pragma unroll
    for (int j = 0; j < 4; ++j)
      #pragma unroll
      for (int r = 0; r < 4; ++r)
        Ct[(r0l + i * 16 + r) * CT_LD + c0l + j * 16] = f2bf(acc[i][j][r]);
  __syncthreads();
  // coalesced writeout: 2048 chunks of 8 u16 (16B), 8 per thread
  #pragma unroll
  for (int it = 0; it < 8; ++it) {
    int chnk = it * 256 + tid;
    int rr = chnk >> 4, cg = chnk & 15;
    uint4 v = *(const uint4*)&Ct[rr * CT_LD + cg * 8];
    *(uint4*)(C + (size_t)(mbase + rr) * ldc + nbase + cg * 8) = v;
  }
}

// ---------------- threshold-based exact top-32 per row ----------------
// 1 block (4 waves) per row; wave w scans quarter-segment w.
// Phase A: branch-free per-lane max -> 256 lane-maxima; T = 32nd largest of
// maxima (guarantee: T <= true 32nd value, >=32 elements >= T).
// Phase B: rescan, collect all elements >= T into LDS buffer (rare pushes).
// Phase C: exact top-32 extraction (value desc, idx asc) merged w/ run list.
__global__ __launch_bounds__(256) void topk_select(const u16* __restrict__ C, int nk, int key_base,
        float* __restrict__ run_sim, int* __restrict__ run_idx) {
  int row = blockIdx.x;
  int tid = threadIdx.x, lane = tid & 63, wv = tid >> 6;
  int seg = nk >> 2;                           // nk multiple of 2048 -> seg multiple of 512
  const u16* crow = C + (size_t)row * nk + (size_t)wv * seg;
  int ibase = key_base + wv * seg;

  __shared__ float lmax[256];
  __shared__ float Tsh;
  __shared__ int cnt;
  __shared__ float bval[TCAP];
  __shared__ int bidx[TCAP];

  #pragma unroll
  for (int k = 0; k < TCAP / 256; ++k) { bval[tid + k * 256] = -FLT_MAX; bidx[tid + k * 256] = INT_MAX; }
  if (tid == 0) cnt = 0;

  // ---- Phase A: per-lane max, pure fmax chain (no branches) ----
  float pm = -FLT_MAX;
  int iters = seg >> 9;                        // 512 keys per wave-iter (8 bf16/lane)
  for (int t = 0; t < iters; ++t) {
    uint4 v = *(const uint4*)(crow + (size_t)t * 512 + lane * 8);
    pm = fmaxf(pm, __uint_as_float(v.x << 16));
    pm = fmaxf(pm, __uint_as_float(v.x & 0xffff0000u));
    pm = fmaxf(pm, __uint_as_float(v.y << 16));
    pm = fmaxf(pm, __uint_as_float(v.y & 0xffff0000u));
    pm = fmaxf(pm, __uint_as_float(v.z << 16));
    pm = fmaxf(pm, __uint_as_float(v.z & 0xffff0000u));
    pm = fmaxf(pm, __uint_as_float(v.w << 16));
    pm = fmaxf(pm, __uint_as_float(v.w & 0xffff0000u));
  }
  lmax[tid] = pm;
  __syncthreads();

  // ---- T = 32nd largest of the 256 lane-maxima (wave 0) ----
  if (wv == 0) {
    float v0 = lmax[lane * 4 + 0];
    float v1 = lmax[lane * 4 + 1];
    float v2 = lmax[lane * 4 + 2];
    float v3 = lmax[lane * 4 + 3];
    float T = 0.f;
    for (int r = 0; r < CAND; ++r) {
      float lm = fmaxf(fmaxf(v0, v1), fmaxf(v2, v3));
      float wm = lm;
      for (int off = 32; off > 0; off >>= 1) wm = fmaxf(wm, __shfl_xor(wm, off));
      if (lm == wm) {            // remove one copy per owning lane (ok to remove >1/round:
        if      (v0 == wm) v0 = -FLT_MAX;   // T only gets smaller -> superset stays valid)
        else if (v1 == wm) v1 = -FLT_MAX;
        else if (v2 == wm) v2 = -FLT_MAX;
        else               v3 = -FLT_MAX;
      }
      T = wm;
    }
    if (lane == 0) Tsh = T;
  }
  __syncthreads();
  float T = Tsh;

  // ---- Phase B: collect all elements >= T (push path rarely taken) ----
  for (int t = 0; t < iters; ++t) {
    uint4 v = *(const uint4*)(crow + (size_t)t * 512 + lane * 8);
    float f0 = __uint_as_float(v.x << 16);
    float f1 = __uint_as_float(v.x & 0xffff0000u);
    float f2 = __uint_as_float(v.y << 16);
    float f3 = __uint_as_float(v.y & 0xffff0000u);
    float f4 = __uint_as_float(v.z << 16);
    float f5 = __uint_as_float(v.z & 0xffff0000u);
    float f6 = __uint_as_float(v.w << 16);
    float f7 = __uint_as_float(v.w & 0xffff0000u);
    float m8 = fmaxf(fmaxf(fmaxf(f0, f1), fmaxf(f2, f3)),
                     fmaxf(fmaxf(f4, f5), fmaxf(f6, f7)));
    if (m8 >= T) {
      int ib = ibase + t * 512 + lane * 8;
      if (f0 >= T) { int p = atomicAdd(&cnt, 1); if (p < TCAP) { bval[p] = f0; bidx[p] = ib + 0; } }
      if (f1 >= T) { int p = atomicAdd(&cnt, 1); if (p < TCAP) { bval[p] = f1; bidx[p] = ib + 1; } }
      if (f2 >= T) { int p = atomicAdd(&cnt, 1); if (p < TCAP) { bval[p] = f2; bidx[p] = ib + 2; } }
      if (f3 >= T) { int p = atomicAdd(&cnt, 1); if (p < TCAP) { bval[p] = f3; bidx[p] = ib + 3; } }
      if (f4 >= T) { int p = atomicAdd(&cnt, 1); if (p < TCAP) { bval[p] = f4; bidx[p] = ib + 4; } }
      if (f5 >= T) { int p = atomicAdd(&cnt, 1); if (p < TCAP) { bval[p] = f5; bidx[p] = ib + 5; } }
      if (f6 >= T) { int p = atomicAdd(&cnt, 1); if (p < TCAP) { bval[p] = f6; bidx[p] = ib + 6; } }
      if (f7 >= T) { int p = atomicAdd(&cnt, 1); if (p < TCAP) { bval[p] = f7; bidx[p] = ib + 7; } }
    }
  }
  __syncthreads();
  // merge previous running list into the buffer (disjoint key ranges -> no dups)
  if (wv == 0 && lane < CAND) {
    int p = atomicAdd(&cnt, 1);
    if (p < TCAP) { bval[p] = run_sim[row * CAND + lane]; bidx[p] = run_idx[row * CAND + lane]; }
  }
  __syncthreads();

  // ---- Phase C: exact top-32 extraction (value desc, idx asc), wave 0 ----
  if (wv == 0) {
    float sv[16]; int si[16];
    #pragma unroll
    for (int k = 0; k < 16; ++k) { sv[k] = bval[lane * 16 + k]; si[k] = bidx[lane * 16 + k]; }
    for (int r = 0; r < CAND; ++r) {
      float lm = -FLT_MAX; int li = INT_MAX;
      #pragma unroll
      for (int k = 0; k < 16; ++k)
        if (sv[k] > lm || (sv[k] == lm && si[k] < li)) { lm = sv[k]; li = si[k]; }
      float plm = lm; int pli = li;
      for (int off = 32; off > 0; off >>= 1) {
        float ov = __shfl_xor(lm, off);
        int   oi = __shfl_xor(li, off);
        if (ov > lm || (ov == lm && oi < li)) { lm = ov; li = oi; }
      }
      if (lane == 0) { run_sim[row * CAND + r] = lm; run_idx[row * CAND + r] = li; }
      if (plm == lm && pli == li) {         // winner lane removes its copy (idx unique)
        bool done = false;
        #pragma unroll
        for (int k = 0; k < 16; ++k)
          if (!done && sv[k] == lm && si[k] == li) { sv[k] = -FLT_MAX; si[k] = INT_MAX; done = true; }
      }
    }
  }
}

// ---------------- exact fp32 rescore of 32 candidates + safety dot ----------------
__global__ __launch_bounds__(64) void rescore(const float* __restrict__ q_norm, const float* __restrict__ mkeys,
        const int* __restrict__ mvals, const int* __restrict__ run_idx, const int* __restrict__ item_saf,
        float* __restrict__ t16_sim, int* __restrict__ t16_val, int* __restrict__ nearest_val,
        float* __restrict__ safety_sim) {
  int row = blockIdx.x, lane = threadIdx.x;
  int b = row / HW;
  const float* qr = q_norm + (size_t)row * KDIM;
  float4 q0 = *(const float4*)(qr + lane * 8);
  float4 q1 = *(const float4*)(qr + lane * 8 + 4);
  __shared__ float es[CAND]; __shared__ int ei[CAND];

  for (int c = 0; c < CAND; ++c) {
    int ki = run_idx[row * CAND + c];
    float p = -FLT_MAX;
    if (ki >= 0 && ki < NKEYS) {
      const float* kr = mkeys + (size_t)ki * KDIM;
      float4 k0 = *(const float4*)(kr + lane * 8);
      float4 k1 = *(const float4*)(kr + lane * 8 + 4);
      p = q0.x * k0.x + q0.y * k0.y + q0.z * k0.z + q0.w * k0.w
        + q1.x * k1.x + q1.y * k1.y + q1.z * k1.z + q1.w * k1.w;
      for (int off = 32; off > 0; off >>= 1) p += __shfl_xor(p, off);
    }
    if (lane == 0) { es[c] = p; ei[c] = (ki >= 0 && ki < NKEYS) ? ki : -1; }
  }
  {
    int ks = item_saf[b];
    const float* kr = mkeys + (size_t)ks * KDIM;
    float4 k0 = *(const float4*)(kr + lane * 8);
    float4 k1 = *(const float4*)(kr + lane * 8 + 4);
    float p = q0.x * k0.x + q0.y * k0.y + q0.z * k0.z + q0.w * k0.w
            + q1.x * k1.x + q1.y * k1.y + q1.z * k1.z + q1.w * k1.w;
    for (int off = 32; off > 0; off >>= 1) p += __shfl_xor(p, off);
    if (lane == 0) safety_sim[row] = p;
  }
  __syncthreads();
  if (lane == 0) {   // exact top-16, tie -> lower key index (jax.lax.top_k)
    for (int r = 0; r < TOPK; ++r) {
      float bs = -FLT_MAX; int bi = INT_MAX, bc = -1;
      for (int c = 0; c < CAND; ++c) {
        if (ei[c] < 0) continue;
        if (es[c] > bs || (es[c] == bs && ei[c] < bi)) { bs = es[c]; bi = ei[c]; bc = c; }
      }
      if (bc < 0) { bs = 0.f; bi = 0; } else ei[bc] = -1;
      t16_sim[row * TOPK + r] = bs;
      t16_val[row * TOPK + r] = mvals[bi];
      if (r == 0) nearest_val[row] = mvals[bi];
    }
  }
}

// ---------------- per-item mode vote + margin loss ----------------
__global__ __launch_bounds__(64) void item_loss(const float* __restrict__ t16_sim, const int* __restrict__ t16_val,
        const int* __restrict__ nearest_val, const float* __restrict__ safety_sim,
        const int* __restrict__ targets, const int* __restrict__ item_ex,
        float* __restrict__ losses, float* __restrict__ out) {
  int b = blockIdx.x, lane = threadIdx.x;
  __shared__ int counts[101];
  counts[lane] = 0;
  if (lane + 64 < 101) counts[lane + 64] = 0;
  __syncthreads();
  float lw = 0.f, lns = 0.f;
  if (lane < HW) {
    int row = b * HW + lane;
    int tgt = targets[b];
    float pos = -FLT_MAX, neg = -FLT_MAX, ns = -FLT_MAX;
    for (int k = 0; k < TOPK; ++k) {
      float sv = t16_sim[row * TOPK + k];
      int vv = t16_val[row * TOPK + k];
      bool m = (vv == tgt);
      pos = fmaxf(pos, m ? sv : 0.0f);   // sims * cmask semantics (zeros included)
      neg = fmaxf(neg, m ? 0.0f : sv);
      ns  = fmaxf(ns,  m ? 0.0f : sv);
    }
    pos = fmaxf(pos, safety_sim[row]);   // safety column: val == tgt -> match
    neg = fmaxf(neg, 0.0f);              // safety contributes 0 to neg
    lw  = fmaxf(neg - pos + ALPHA_C, 0.0f);
    lns = fmaxf(ns + ALPHA_C, 0.0f);
    atomicAdd(&counts[nearest_val[row] + 1], 1);
  }
  __syncthreads();
  for (int off = 32; off > 0; off >>= 1) {
    lw  += __shfl_xor(lw, off);
    lns += __shfl_xor(lns, off);
  }
  if (lane == 0) {
    int bi = 0, bc = counts[0];
    for (int c = 1; c < 101; ++c)
      if (counts[c] > bc) { bc = counts[c]; bi = c; }   // first max (argmax)
    out[b] = (float)(bi - 1);
    losses[b] = (item_ex[b] ? lw : lns) / 49.0f;        // mean over hw
  }
}

__global__ __launch_bounds__(64) void final_sum(const float* __restrict__ losses, float* __restrict__ out) {
  int lane = threadIdx.x;
  float v = losses[lane];
  for (int off = 32; off > 0; off >>= 1) v += __shfl_xor(v, off);
  if (lane == 0) out[NITEMS] = v;
}

// ---------------- launch ----------------
extern "C" void kernel_launch(void* const* d_in, const int* in_sizes, int n_in,
                              void* d_out, int out_size, void* d_ws, size_t ws_size,
                              hipStream_t stream) {
  const float* queries = (const float*)d_in[0];
  const int*   targets = (const int*)d_in[1];
  const float* m_keys  = (const float*)d_in[2];
  const int*   m_vals  = (const int*)d_in[3];
  float* out = (float*)d_out;
  char* ws = (char*)d_ws;

  size_t off = 0;
  auto alloc = [&](size_t bytes) -> char* {
    char* p = ws + off;
    off += (bytes + 255) & ~(size_t)255;
    return p;
  };
  float* q_norm   = (float*)alloc((size_t)NROWS * KDIM * 4);
  u16*   qbf      = (u16*)  alloc((size_t)NROWS_PAD * KDIM * 2);
  u16*   kbf      = (u16*)  alloc((size_t)NKEYS * KDIM * 2);
  int*   first_ix = (int*)  alloc(128 * 4);
  int*   item_saf = (int*)  alloc(64 * 4);
  int*   item_ex  = (int*)  alloc(64 * 4);
  float* run_sim  = (float*)alloc((size_t)NROWS * CAND * 4);
  int*   run_idx  = (int*)  alloc((size_t)NROWS * CAND * 4);
  float* t16s     = (float*)alloc((size_t)NROWS * TOPK * 4);
  int*   t16v     = (int*)  alloc((size_t)NROWS * TOPK * 4);
  int*   nearv    = (int*)  alloc((size_t)NROWS * 4);
  float* safs     = (float*)alloc((size_t)NROWS * 4);
  float* losses   = (float*)alloc(64 * 4);
  u16*   sims     = (u16*)(ws + off);

  // size the sims chunk from remaining workspace (multiple of 2048 keys so
  // each wave's quarter-segment stays a multiple of 512); cap at CHUNK_MAX so
  // the sims slab (3200 * chunk * 2B) stays Infinity-Cache-resident.
  size_t avail = ws_size > off ? ws_size - off : 0;
  long long maxkeys = (long long)(avail / ((size_t)NROWS_PAD * 2));
  int chunk = (int)((maxkeys / 2048) * 2048);
  if (chunk > CHUNK_MAX) chunk = CHUNK_MAX;
  if (chunk < 2048) chunk = 2048;

  hipLaunchKernelGGL(prep_qnorm, dim3(NROWS_PAD), dim3(256), 0, stream, queries, q_norm, qbf);
  hipLaunchKernelGGL(prep_keys, dim3((NKEYS * KDIM) / 2048), dim3(256), 0, stream, m_keys, kbf);
  hipLaunchKernelGGL(init_first, dim3(1), dim3(128), 0, stream, first_ix);
  hipLaunchKernelGGL(init_run, dim3((NROWS * CAND) / 256), dim3(256), 0, stream, run_sim, run_idx);
  hipLaunchKernelGGL(scan_vals, dim3(NKEYS / 256), dim3(256), 0, stream, m_vals, first_ix);
  hipLaunchKernelGGL(item_info, dim3(1), dim3(64), 0, stream, targets, first_ix, item_saf, item_ex);

  for (int base = 0; base < NKEYS; base += chunk) {
    int nk = (NKEYS - base < chunk) ? (NKEYS - base) : chunk;
    hipLaunchKernelGGL(gemm_chunk, dim3(NROWS_PAD / 128, nk / 128), dim3(256), 0, stream,
                       qbf, kbf + (size_t)base * KDIM, sims, nk);
    hipLaunchKernelGGL(topk_select, dim3(NROWS), dim3(256), 0, stream, sims, nk, base, run_sim, run_idx);
  }

  hipLaunchKernelGGL(rescore, dim3(NROWS), dim3(64), 0, stream,
                     q_norm, m_keys, m_vals, run_idx, item_saf, t16s, t16v, nearv, safs);
  hipLaunchKernelGGL(item_loss, dim3(64), dim3(64), 0, stream,
                     t16s, t16v, nearv, safs, targets, item_ex, losses, out);
  hipLaunchKernelGGL(final_sum, dim3(1), dim3(64), 0, stream, losses, out);
}

// Round 7
// 1029.988 us; speedup vs baseline: 1.2562x; 1.2562x over previous
//
#include <hip/hip_runtime.h>
#include <hip/hip_bf16.h>
#include <float.h>
#include <limits.h>

// ---- problem constants ----
#define NROWS 3136        // 64 items * 49 positions
#define NROWS_PAD 3200    // padded to 25 * 128 for GEMM tiles
#define NKEYS 65536
#define KDIM 512
#define NITEMS 64
#define HW 49
#define TOPK 16
#define CAND 32           // candidates kept per row (margin for exact rescore)
#define TCAP 1024         // LDS collection buffer capacity per row
#define NTILES 512        // 65536 / 128 key-tiles
#define ALPHA_C 0.1f

typedef unsigned short u16;
typedef unsigned int u32;
typedef __attribute__((ext_vector_type(8))) short bfrag;   // 8 bf16 = 4 VGPR (MFMA A/B frag)
typedef __attribute__((ext_vector_type(4))) float f32x4;   // MFMA C/D frag

// round-to-nearest-even f32 -> bf16 bits (inputs finite)
__device__ inline u16 f2bf(float x) {
  u32 u = __float_as_uint(x);
  u32 r = u + 0x7fffu + ((u >> 16) & 1u);
  return (u16)(r >> 16);
}

// ---------------- prep: normalize queries ----------------
// queries layout (64, 512, 7, 7): q[b,p,c] = queries[b*512*49 + c*49 + p]
__global__ __launch_bounds__(256) void prep_qnorm(const float* __restrict__ q,
        float* __restrict__ q_norm, u16* __restrict__ qbf) {
  int row = blockIdx.x;
  int t = threadIdx.x;
  if (row >= NROWS) {            // pad rows: zero bf16 so GEMM is defined
    qbf[(size_t)row * KDIM + t] = 0;
    qbf[(size_t)row * KDIM + t + 256] = 0;
    return;
  }
  int b = row / HW, p = row % HW;
  const float* base = q + (size_t)b * KDIM * HW + p;
  float v0 = base[(size_t)t * HW];
  float v1 = base[(size_t)(t + 256) * HW];
  __shared__ float red[256];
  red[t] = v0 * v0 + v1 * v1;
  __syncthreads();
  for (int st = 128; st > 0; st >>= 1) {
    if (t < st) red[t] += red[t + st];
    __syncthreads();
  }
  float nrm = fmaxf(sqrtf(red[0]), 1e-12f);   // clip(norm, 1e-12)
  float w0 = v0 / nrm, w1 = v1 / nrm;
  q_norm[(size_t)row * KDIM + t] = w0;
  q_norm[(size_t)row * KDIM + t + 256] = w1;
  qbf[(size_t)row * KDIM + t] = f2bf(w0);
  qbf[(size_t)row * KDIM + t + 256] = f2bf(w1);
}

// ---------------- prep: keys -> bf16 ----------------
__global__ __launch_bounds__(256) void prep_keys(const float* __restrict__ mk, u16* __restrict__ kbf) {
  size_t i = ((size_t)blockIdx.x * 256 + threadIdx.x) * 8;
  float4 a = *(const float4*)(mk + i);
  float4 b = *(const float4*)(mk + i + 4);
  bfrag v;
  v[0] = (short)f2bf(a.x); v[1] = (short)f2bf(a.y);
  v[2] = (short)f2bf(a.z); v[3] = (short)f2bf(a.w);
  v[4] = (short)f2bf(b.x); v[5] = (short)f2bf(b.y);
  v[6] = (short)f2bf(b.z); v[7] = (short)f2bf(b.w);
  *(bfrag*)(kbf + i) = v;
}

// ---------------- misc init / class scan ----------------
__global__ void init_first(int* first_idx) {
  int t = threadIdx.x;
  if (t < 100) first_idx[t] = INT_MAX;
}
__global__ __launch_bounds__(256) void init_run(float* run_sim, int* run_idx) {
  int i = blockIdx.x * 256 + threadIdx.x;   // NROWS*CAND entries exactly
  run_sim[i] = -FLT_MAX;
  run_idx[i] = INT_MAX;
}
__global__ __launch_bounds__(256) void scan_vals(const int* __restrict__ mvals, int* first_idx) {
  int i = blockIdx.x * 256 + threadIdx.x;
  atomicMin(&first_idx[mvals[i]], i);       // first occurrence == argmax(hit)
}
__global__ void item_info(const int* __restrict__ targets, const int* __restrict__ first_idx,
                          int* item_saf, int* item_ex) {
  int b = threadIdx.x;   // 64
  int fi = first_idx[targets[b]];
  int ex = (fi != INT_MAX);
  item_ex[b] = ex;
  item_saf[b] = ex ? fi : 0;   // argmax(all-False) == 0 in reference
}

// ---------------- bf16 MFMA GEMM + fused per-row tile-max ----------------
// m97-style 128x128 tile, BK=32, 4 waves, global_load_lds width 16.
// Grid: x = row-panel (25, fastest) so consecutive blocks reuse one B-tile
// from L2; y = key-tile. Epilogue additionally computes, per row, the max of
// the 128 bf16-ROUNDED sims of this tile (same value space as stored sims)
// and writes it to tilemax[row][tile] — selection never rescans sims.
__device__ inline void gload16(const void* g, void* l) {
  __builtin_amdgcn_global_load_lds((const __attribute__((address_space(1))) unsigned int*)g,
                                   (__attribute__((address_space(3))) unsigned int*)l, 16, 0, 0);
}

#define CT_LD 144   // u16 elements per Ct row (288B; keeps 16B alignment per row)

__global__ __launch_bounds__(256) void gemm_chunk(const u16* __restrict__ A, const u16* __restrict__ B,
        u16* __restrict__ C, int ldc, float* __restrict__ tilemax, int tile_base) {
  __shared__ __align__(16) char lds[128 * CT_LD * 2 + 128 * 2 * 4];  // Ct + rmax
  u16* As = (u16*)lds;                                  // [128][32]
  u16* Bs = (u16*)(lds + 8192);                         // [128][32]
  u16* Ct = (u16*)lds;                                  // [128][CT_LD]
  float* rmaxL = (float*)(lds + 128 * CT_LD * 2);       // [128][2]
  int tid = threadIdx.x;
  int lane = tid & 63, wv = tid >> 6;
  int wr = wv >> 1, wc = wv & 1;
  int mbase = blockIdx.x * 128;   // row panel (fastest-varying)
  int nbase = blockIdx.y * 128;   // key tile
  const u16* Ag = A + (size_t)mbase * KDIM;
  const u16* Bg = B + (size_t)nbase * KDIM;

  f32x4 acc[4][4];
  #pragma unroll
  for (int i = 0; i < 4; ++i)
    #pragma unroll
    for (int j = 0; j < 4; ++j)
      acc[i][j] = (f32x4){0.f, 0.f, 0.f, 0.f};

  int lrow = lane & 15;
  int k8 = (lane >> 4) * 8;     // contiguous 8-bf16 K-slice per lane

  for (int kk = 0; kk < KDIM; kk += 32) {
    #pragma unroll
    for (int s = 0; s < 2; ++s) {
      int ch = s * 256 + wv * 64 + lane;      // 512 x 16B chunks per 8KB tile
      int r = ch >> 2, c = (ch & 3) * 8;
      gload16(Ag + (size_t)r * KDIM + kk + c, lds + (size_t)(s * 256 + wv * 64) * 16);
      gload16(Bg + (size_t)r * KDIM + kk + c, lds + 8192 + (size_t)(s * 256 + wv * 64) * 16);
    }
    __syncthreads();
    bfrag a[4], b[4];
    #pragma unroll
    for (int i = 0; i < 4; ++i) {
      a[i] = *(const bfrag*)&As[(wr * 64 + i * 16 + lrow) * 32 + k8];
      b[i] = *(const bfrag*)&Bs[(wc * 64 + i * 16 + lrow) * 32 + k8];
    }
    #pragma unroll
    for (int i = 0; i < 4; ++i)
      #pragma unroll
      for (int j = 0; j < 4; ++j)
        acc[i][j] = __builtin_amdgcn_mfma_f32_16x16x32_bf16(a[i], b[j], acc[i][j], 0, 0, 0);
    __syncthreads();   // also protects the Ct alias below on the last iteration
  }
  // C/D layout: col = lane&15, row = (lane>>4)*4 + reg  [m89-verified]
  int h = lane >> 4;
  int r0l = wr * 64 + h * 4;
  int c0l = wc * 64 + lrow;
  #pragma unroll
  for (int i = 0; i < 4; ++i)
    #pragma unroll
    for (int r = 0; r < 4; ++r) {
      float m = -FLT_MAX;
      #pragma unroll
      for (int j = 0; j < 4; ++j) {
        u16 bb = f2bf(acc[i][j][r]);
        Ct[(r0l + i * 16 + r) * CT_LD + c0l + j * 16] = bb;
        m = fmaxf(m, __uint_as_float((u32)bb << 16));   // bf16-rounded value
      }
      // reduce across the 16 lanes sharing this row (contiguous lane group)
      #pragma unroll
      for (int off = 1; off < 16; off <<= 1) m = fmaxf(m, __shfl_xor(m, off));
      if (lrow == 0) rmaxL[(r0l + i * 16 + r) * 2 + wc] = m;
    }
  __syncthreads();
  // coalesced writeout: 2048 chunks of 8 u16 (16B), 8 per thread
  #pragma unroll
  for (int it = 0; it < 8; ++it) {
    int chnk = it * 256 + tid;
    int rr = chnk >> 4, cg = chnk & 15;
    uint4 v = *(const uint4*)&Ct[rr * CT_LD + cg * 8];
    *(uint4*)(C + (size_t)(mbase + rr) * ldc + nbase + cg * 8) = v;
  }
  if (tid < 128) {
    float tm = fmaxf(rmaxL[tid * 2], rmaxL[tid * 2 + 1]);
    tilemax[(size_t)(mbase + tid) * NTILES + tile_base + blockIdx.y] = tm;
  }
}

// ---------------- tilemax-guided exact top-32 per row ----------------
// 1 block (4 waves) per row. T = 32nd largest of the chunk's NT tile-maxima
// (removal loop, computed redundantly per wave). Counting argument:
// >=32 tiles have max >= T -> >=32 elements >= T, and T <= true 32nd value,
// so {elements >= T} is a superset of the true (bf16) top-32. Only tiles
// with max >= T (~32-45 of 512) are gathered — no full sims rescan.
__global__ __launch_bounds__(256) void topk_select(const u16* __restrict__ C, int nk, int key_base,
        const float* __restrict__ tilemax, int tile_base,
        float* __restrict__ run_sim, int* __restrict__ run_idx) {
  int row = blockIdx.x;
  int tid = threadIdx.x, lane = tid & 63, wv = tid >> 6;
  int NT = nk >> 7;                           // chunk >= 4096 -> NT >= 32
  const float* tmrow = tilemax + (size_t)row * NTILES + tile_base;

  __shared__ int tlist[NTILES];
  __shared__ int tcnt;
  __shared__ int cnt;
  __shared__ float bval[TCAP];
  __shared__ int bidx[TCAP];
  #pragma unroll
  for (int k = 0; k < TCAP / 256; ++k) { bval[tid + k * 256] = -FLT_MAX; bidx[tid + k * 256] = INT_MAX; }
  if (tid == 0) { tcnt = 0; cnt = 0; }
  __syncthreads();

  // ---- T = 32nd largest tile-max (each wave redundantly; 8 regs/lane) ----
  float v[8];
  #pragma unroll
  for (int k = 0; k < 8; ++k)
    v[k] = (lane + 64 * k < NT) ? tmrow[lane + 64 * k] : -FLT_MAX;
  float T = 0.f;
  for (int r = 0; r < CAND; ++r) {
    float lm = v[0];
    #pragma unroll
    for (int k = 1; k < 8; ++k) lm = fmaxf(lm, v[k]);
    for (int off = 32; off > 0; off >>= 1) lm = fmaxf(lm, __shfl_xor(lm, off));
    #pragma unroll
    for (int k = 0; k < 8; ++k) if (v[k] == lm) v[k] = -FLT_MAX;  // ties removed together: T only shrinks (safe)
    T = lm;
  }

  // ---- selected tiles ----
  for (int t = tid; t < NT; t += 256)
    if (tmrow[t] >= T) { int p = atomicAdd(&tcnt, 1); tlist[p] = t; }
  __syncthreads();

  // ---- gather candidates from selected tiles only ----
  int ntl = tcnt;
  const u16* crow = C + (size_t)row * nk;
  for (int e = wv; e < ntl; e += 4) {
    int tile = tlist[e];
    u32 pair = *(const u32*)(crow + (size_t)tile * 128 + lane * 2);  // 2 bf16/lane, 256B/wave
    float f0 = __uint_as_float(pair << 16);
    float f1 = __uint_as_float(pair & 0xffff0000u);
    int ib = key_base + tile * 128 + lane * 2;
    if (f0 >= T) { int p = atomicAdd(&cnt, 1); if (p < TCAP) { bval[p] = f0; bidx[p] = ib; } }
    if (f1 >= T) { int p = atomicAdd(&cnt, 1); if (p < TCAP) { bval[p] = f1; bidx[p] = ib + 1; } }
  }
  __syncthreads();
  // merge previous running list into the buffer (disjoint key ranges -> no dups)
  if (wv == 0 && lane < CAND) {
    int p = atomicAdd(&cnt, 1);
    if (p < TCAP) { bval[p] = run_sim[row * CAND + lane]; bidx[p] = run_idx[row * CAND + lane]; }
  }
  __syncthreads();

  // ---- exact top-32 extraction (value desc, idx asc), wave 0 ----
  if (wv == 0) {
    float sv[16]; int si[16];
    #pragma unroll
    for (int k = 0; k < 16; ++k) { sv[k] = bval[lane * 16 + k]; si[k] = bidx[lane * 16 + k]; }
    for (int r = 0; r < CAND; ++r) {
      float lm = -FLT_MAX; int li = INT_MAX;
      #pragma unroll
      for (int k = 0; k < 16; ++k)
        if (sv[k] > lm || (sv[k] == lm && si[k] < li)) { lm = sv[k]; li = si[k]; }
      float plm = lm; int pli = li;
      for (int off = 32; off > 0; off >>= 1) {
        float ov = __shfl_xor(lm, off);
        int   oi = __shfl_xor(li, off);
        if (ov > lm || (ov == lm && oi < li)) { lm = ov; li = oi; }
      }
      if (lane == 0) { run_sim[row * CAND + r] = lm; run_idx[row * CAND + r] = li; }
      if (plm == lm && pli == li) {         // winner lane removes its copy (idx unique)
        bool done = false;
        #pragma unroll
        for (int k = 0; k < 16; ++k)
          if (!done && sv[k] == lm && si[k] == li) { sv[k] = -FLT_MAX; si[k] = INT_MAX; done = true; }
      }
    }
  }
}

// ---------------- exact fp32 rescore of 32 candidates + safety dot ----------------
__global__ __launch_bounds__(64) void rescore(const float* __restrict__ q_norm, const float* __restrict__ mkeys,
        const int* __restrict__ mvals, const int* __restrict__ run_idx, const int* __restrict__ item_saf,
        float* __restrict__ t16_sim, int* __restrict__ t16_val, int* __restrict__ nearest_val,
        float* __restrict__ safety_sim) {
  int row = blockIdx.x, lane = threadIdx.x;
  int b = row / HW;
  const float* qr = q_norm + (size_t)row * KDIM;
  float4 q0 = *(const float4*)(qr + lane * 8);
  float4 q1 = *(const float4*)(qr + lane * 8 + 4);
  __shared__ float es[CAND]; __shared__ int ei[CAND];

  for (int c = 0; c < CAND; ++c) {
    int ki = run_idx[row * CAND + c];
    float p = -FLT_MAX;
    if (ki >= 0 && ki < NKEYS) {
      const float* kr = mkeys + (size_t)ki * KDIM;
      float4 k0 = *(const float4*)(kr + lane * 8);
      float4 k1 = *(const float4*)(kr + lane * 8 + 4);
      p = q0.x * k0.x + q0.y * k0.y + q0.z * k0.z + q0.w * k0.w
        + q1.x * k1.x + q1.y * k1.y + q1.z * k1.z + q1.w * k1.w;
      for (int off = 32; off > 0; off >>= 1) p += __shfl_xor(p, off);
    }
    if (lane == 0) { es[c] = p; ei[c] = (ki >= 0 && ki < NKEYS) ? ki : -1; }
  }
  {
    int ks = item_saf[b];
    const float* kr = mkeys + (size_t)ks * KDIM;
    float4 k0 = *(const float4*)(kr + lane * 8);
    float4 k1 = *(const float4*)(kr + lane * 8 + 4);
    float p = q0.x * k0.x + q0.y * k0.y + q0.z * k0.z + q0.w * k0.w
            + q1.x * k1.x + q1.y * k1.y + q1.z * k1.z + q1.w * k1.w;
    for (int off = 32; off > 0; off >>= 1) p += __shfl_xor(p, off);
    if (lane == 0) safety_sim[row] = p;
  }
  __syncthreads();
  if (lane == 0) {   // exact top-16, tie -> lower key index (jax.lax.top_k)
    for (int r = 0; r < TOPK; ++r) {
      float bs = -FLT_MAX; int bi = INT_MAX, bc = -1;
      for (int c = 0; c < CAND; ++c) {
        if (ei[c] < 0) continue;
        if (es[c] > bs || (es[c] == bs && ei[c] < bi)) { bs = es[c]; bi = ei[c]; bc = c; }
      }
      if (bc < 0) { bs = 0.f; bi = 0; } else ei[bc] = -1;
      t16_sim[row * TOPK + r] = bs;
      t16_val[row * TOPK + r] = mvals[bi];
      if (r == 0) nearest_val[row] = mvals[bi];
    }
  }
}

// ---------------- per-item mode vote + margin loss ----------------
__global__ __launch_bounds__(64) void item_loss(const float* __restrict__ t16_sim, const int* __restrict__ t16_val,
        const int* __restrict__ nearest_val, const float* __restrict__ safety_sim,
        const int* __restrict__ targets, const int* __restrict__ item_ex,
        float* __restrict__ losses, float* __restrict__ out) {
  int b = blockIdx.x, lane = threadIdx.x;
  __shared__ int counts[101];
  counts[lane] = 0;
  if (lane + 64 < 101) counts[lane + 64] = 0;
  __syncthreads();
  float lw = 0.f, lns = 0.f;
  if (lane < HW) {
    int row = b * HW + lane;
    int tgt = targets[b];
    float pos = -FLT_MAX, neg = -FLT_MAX, ns = -FLT_MAX;
    for (int k = 0; k < TOPK; ++k) {
      float sv = t16_sim[row * TOPK + k];
      int vv = t16_val[row * TOPK + k];
      bool m = (vv == tgt);
      pos = fmaxf(pos, m ? sv : 0.0f);   // sims * cmask semantics (zeros included)
      neg = fmaxf(neg, m ? 0.0f : sv);
      ns  = fmaxf(ns,  m ? 0.0f : sv);
    }
    pos = fmaxf(pos, safety_sim[row]);   // safety column: val == tgt -> match
    neg = fmaxf(neg, 0.0f);              // safety contributes 0 to neg
    lw  = fmaxf(neg - pos + ALPHA_C, 0.0f);
    lns = fmaxf(ns + ALPHA_C, 0.0f);
    atomicAdd(&counts[nearest_val[row] + 1], 1);
  }
  __syncthreads();
  for (int off = 32; off > 0; off >>= 1) {
    lw  += __shfl_xor(lw, off);
    lns += __shfl_xor(lns, off);
  }
  if (lane == 0) {
    int bi = 0, bc = counts[0];
    for (int c = 1; c < 101; ++c)
      if (counts[c] > bc) { bc = counts[c]; bi = c; }   // first max (argmax)
    out[b] = (float)(bi - 1);
    losses[b] = (item_ex[b] ? lw : lns) / 49.0f;        // mean over hw
  }
}

__global__ __launch_bounds__(64) void final_sum(const float* __restrict__ losses, float* __restrict__ out) {
  int lane = threadIdx.x;
  float v = losses[lane];
  for (int off = 32; off > 0; off >>= 1) v += __shfl_xor(v, off);
  if (lane == 0) out[NITEMS] = v;
}

// ---------------- launch ----------------
extern "C" void kernel_launch(void* const* d_in, const int* in_sizes, int n_in,
                              void* d_out, int out_size, void* d_ws, size_t ws_size,
                              hipStream_t stream) {
  const float* queries = (const float*)d_in[0];
  const int*   targets = (const int*)d_in[1];
  const float* m_keys  = (const float*)d_in[2];
  const int*   m_vals  = (const int*)d_in[3];
  float* out = (float*)d_out;
  char* ws = (char*)d_ws;

  size_t off = 0;
  auto alloc = [&](size_t bytes) -> char* {
    char* p = ws + off;
    off += (bytes + 255) & ~(size_t)255;
    return p;
  };
  float* q_norm   = (float*)alloc((size_t)NROWS * KDIM * 4);
  u16*   qbf      = (u16*)  alloc((size_t)NROWS_PAD * KDIM * 2);
  u16*   kbf      = (u16*)  alloc((size_t)NKEYS * KDIM * 2);
  float* tilemax  = (float*)alloc((size_t)NROWS_PAD * NTILES * 4);
  int*   first_ix = (int*)  alloc(128 * 4);
  int*   item_saf = (int*)  alloc(64 * 4);
  int*   item_ex  = (int*)  alloc(64 * 4);
  float* run_sim  = (float*)alloc((size_t)NROWS * CAND * 4);
  int*   run_idx  = (int*)  alloc((size_t)NROWS * CAND * 4);
  float* t16s     = (float*)alloc((size_t)NROWS * TOPK * 4);
  int*   t16v     = (int*)  alloc((size_t)NROWS * TOPK * 4);
  int*   nearv    = (int*)  alloc((size_t)NROWS * 4);
  float* safs     = (float*)alloc((size_t)NROWS * 4);
  float* losses   = (float*)alloc(64 * 4);
  u16*   sims     = (u16*)(ws + off);

  // sims chunk from remaining ws: multiple of 4096 keys (NT >= 32 per chunk),
  // full 65536 preferred (observed ws fits: R3 ran a single full chunk).
  size_t avail = ws_size > off ? ws_size - off : 0;
  long long maxkeys = (long long)(avail / ((size_t)NROWS_PAD * 2));
  int chunk = (int)((maxkeys / 4096) * 4096);
  if (chunk > NKEYS) chunk = NKEYS;
  if (chunk < 4096) chunk = 4096;

  hipLaunchKernelGGL(prep_qnorm, dim3(NROWS_PAD), dim3(256), 0, stream, queries, q_norm, qbf);
  hipLaunchKernelGGL(prep_keys, dim3((NKEYS * KDIM) / 2048), dim3(256), 0, stream, m_keys, kbf);
  hipLaunchKernelGGL(init_first, dim3(1), dim3(128), 0, stream, first_ix);
  hipLaunchKernelGGL(init_run, dim3((NROWS * CAND) / 256), dim3(256), 0, stream, run_sim, run_idx);
  hipLaunchKernelGGL(scan_vals, dim3(NKEYS / 256), dim3(256), 0, stream, m_vals, first_ix);
  hipLaunchKernelGGL(item_info, dim3(1), dim3(64), 0, stream, targets, first_ix, item_saf, item_ex);

  for (int base = 0; base < NKEYS; base += chunk) {
    int nk = (NKEYS - base < chunk) ? (NKEYS - base) : chunk;
    hipLaunchKernelGGL(gemm_chunk, dim3(NROWS_PAD / 128, nk / 128), dim3(256), 0, stream,
                       qbf, kbf + (size_t)base * KDIM, sims, nk, tilemax, base >> 7);
    hipLaunchKernelGGL(topk_select, dim3(NROWS), dim3(256), 0, stream,
                       sims, nk, base, tilemax, base >> 7, run_sim, run_idx);
  }

  hipLaunchKernelGGL(rescore, dim3(NROWS), dim3(64), 0, stream,
                     q_norm, m_keys, m_vals, run_idx, item_saf, t16s, t16v, nearv, safs);
  hipLaunchKernelGGL(item_loss, dim3(64), dim3(64), 0, stream,
                     t16s, t16v, nearv, safs, targets, item_ex, losses, out);
  hipLaunchKernelGGL(final_sum, dim3(1), dim3(64), 0, stream, losses, out);
}